// Round 1
// baseline (210.851 us; speedup 1.0000x reference)
//
#include <hip/hip_runtime.h>
#include <math.h>

#define GHM_DELTA 0.1f
#define GHM_EPS   1e-12f

__device__ __forceinline__ float softplus_ref(float x) {
    // jax.nn.softplus(x) == jnp.logaddexp(x, 0) == max(x,0) + log1p(exp(-|x|))
    return fmaxf(x, 0.0f) + log1pf(expf(-fabsf(x)));
}

__device__ __forceinline__ float sigmoid_ref(float x) {
    return 1.0f / (1.0f + expf(-x));
}

// One block = 256 threads; each block stages the FULL g vector (N*4 bytes,
// N=16384 -> 64KB LDS) and each thread handles one output index i.
__global__ __launch_bounds__(256) void ghm_main_kernel(
    const float* __restrict__ logits,
    const int*   __restrict__ targets,
    const float* __restrict__ pos_weight,
    double*      __restrict__ partials,   // [gridDim.x * 2]
    int n)
{
    extern __shared__ float g_lds[];      // n floats (64KB for n=16384)

    const int tid = threadIdx.x;
    const int bid = blockIdx.x;

    // Stage g[j] = |sigmoid(x_j) - y_j| into LDS (block-local recompute; the
    // 128KB of inputs are L2/L3 resident so this is cheap and removes any
    // inter-block dependency).
    for (int j = tid; j < n; j += blockDim.x) {
        float x = logits[j];
        float y = (float)targets[j];
        g_lds[j] = fabsf(sigmoid_ref(x) - y);
    }
    __syncthreads();

    const int i = bid * blockDim.x + tid;
    float w_val = 0.0f, p_val = 0.0f;
    if (i < n) {
        float x = logits[i];
        float y = (float)targets[i];
        float gi = fabsf(sigmoid_ref(x) - y);

        int count = 0;
        const int n4 = n >> 2;
        const float4* g4 = reinterpret_cast<const float4*>(g_lds);
        #pragma unroll 8
        for (int j = 0; j < n4; ++j) {
            float4 v = g4[j];   // uniform address across wave -> LDS broadcast
            count += (fabsf(gi - v.x) <= GHM_DELTA) ? 1 : 0;
            count += (fabsf(gi - v.y) <= GHM_DELTA) ? 1 : 0;
            count += (fabsf(gi - v.z) <= GHM_DELTA) ? 1 : 0;
            count += (fabsf(gi - v.w) <= GHM_DELTA) ? 1 : 0;
        }
        for (int j = n4 << 2; j < n; ++j) {
            count += (fabsf(gi - g_lds[j]) <= GHM_DELTA) ? 1 : 0;
        }

        float GD   = (float)count / GHM_DELTA;          // matches sum(...)/DELTA in fp32
        float beta = (float)n / (GD + GHM_EPS);
        float pw   = pos_weight[0];
        float per  = pw * y * softplus_ref(-x) + (1.0f - y) * softplus_ref(x);
        w_val = beta * per;
        p_val = per;
    }

    // Deterministic block reduction in double (wave shfl -> LDS -> thread 0).
    double wd = (double)w_val;
    double pd = (double)p_val;
    #pragma unroll
    for (int off = 32; off >= 1; off >>= 1) {
        wd += __shfl_down(wd, off, 64);
        pd += __shfl_down(pd, off, 64);
    }
    __syncthreads();                       // everyone done reading g_lds
    double* red = reinterpret_cast<double*>(g_lds);  // reuse LDS as scratch
    const int nwaves = blockDim.x >> 6;
    const int wave = tid >> 6;
    if ((tid & 63) == 0) { red[wave * 2] = wd; red[wave * 2 + 1] = pd; }
    __syncthreads();
    if (tid == 0) {
        double sw = 0.0, sp = 0.0;
        for (int k = 0; k < nwaves; ++k) { sw += red[k * 2]; sp += red[k * 2 + 1]; }
        partials[bid * 2]     = sw;
        partials[bid * 2 + 1] = sp;
    }
}

// Single-wave deterministic final reduce.
__global__ __launch_bounds__(64) void ghm_final_kernel(
    const double* __restrict__ partials,
    float* __restrict__ out,
    int nblocks, int n)
{
    double sw = 0.0, sp = 0.0;
    for (int k = threadIdx.x; k < nblocks; k += 64) {
        sw += partials[k * 2];
        sp += partials[k * 2 + 1];
    }
    #pragma unroll
    for (int off = 32; off >= 1; off >>= 1) {
        sw += __shfl_down(sw, off, 64);
        sp += __shfl_down(sp, off, 64);
    }
    if (threadIdx.x == 0) {
        out[0] = (float)(sw / (double)n);  // weighted mean
        out[1] = (float)(sp / (double)n);  // pure mean
    }
}

extern "C" void kernel_launch(void* const* d_in, const int* in_sizes, int n_in,
                              void* d_out, int out_size, void* d_ws, size_t ws_size,
                              hipStream_t stream) {
    const float* logits     = (const float*)d_in[0];
    const int*   targets    = (const int*)d_in[1];
    const float* pos_weight = (const float*)d_in[2];
    float* out = (float*)d_out;
    const int n = in_sizes[0];

    const int block = 256;
    const int grid  = (n + block - 1) / block;
    double* partials = (double*)d_ws;     // grid*2 doubles, well under ws_size

    const size_t lds_bytes = (size_t)n * sizeof(float);  // 64KB for n=16384
    ghm_main_kernel<<<grid, block, lds_bytes, stream>>>(
        logits, targets, pos_weight, partials, n);
    ghm_final_kernel<<<1, 64, 0, stream>>>(partials, out, grid, n);
}

// Round 2
// 37.449 us; speedup vs baseline: 5.6303x; 5.6303x over previous
//
#include <hip/hip_runtime.h>
#include <math.h>

#define GHM_DELTA 0.1f
#define GHM_EPS   1e-12f
#define JCHUNK    1024            // j elements per block (4 KB LDS)
#define NJCHUNK   16              // 16384 / JCHUNK

__device__ __forceinline__ float softplus_ref(float x) {
    // jax.nn.softplus(x) == max(x,0) + log1p(exp(-|x|))
    return fmaxf(x, 0.0f) + log1pf(expf(-fabsf(x)));
}

__device__ __forceinline__ float sigmoid_ref(float x) {
    return 1.0f / (1.0f + expf(-x));
}

// Phase 1: g[i] = |sigmoid(x_i) - y_i|, count[i] = 0 (ws is poison-filled).
__global__ __launch_bounds__(256) void ghm_prep(
    const float* __restrict__ logits, const int* __restrict__ targets,
    float* __restrict__ g, int* __restrict__ count, int n)
{
    int i = blockIdx.x * 256 + threadIdx.x;
    if (i < n) {
        float x = logits[i];
        float y = (float)targets[i];
        g[i] = fabsf(sigmoid_ref(x) - y);
        count[i] = 0;
    }
}

// Phase 2 (hot): grid (n/256, NJCHUNK). Block (bx,by) compares i-tile
// [bx*256, bx*256+256) against j-chunk [by*JCHUNK, ...+JCHUNK).
// Integer atomicAdd partials -> order-invariant, bit-deterministic.
__global__ __launch_bounds__(256) void ghm_pair_count(
    const float* __restrict__ g, int* __restrict__ count, int n)
{
    __shared__ float gj[JCHUNK];
    const int tid = threadIdx.x;
    const int jbase = blockIdx.y * JCHUNK;

    // Stage j-chunk: 256 threads x 1 float4 = 1024 floats.
    reinterpret_cast<float4*>(gj)[tid] =
        reinterpret_cast<const float4*>(g + jbase)[tid];
    __syncthreads();

    const int i = blockIdx.x * 256 + tid;
    const float gi = g[i];

    int c0 = 0, c1 = 0, c2 = 0, c3 = 0;   // 4 independent chains for ILP
    const float4* l4 = reinterpret_cast<const float4*>(gj);
    #pragma unroll 8
    for (int j = 0; j < JCHUNK / 4; ++j) {
        float4 v = l4[j];                 // uniform addr -> LDS broadcast
        c0 += (fabsf(gi - v.x) <= GHM_DELTA) ? 1 : 0;
        c1 += (fabsf(gi - v.y) <= GHM_DELTA) ? 1 : 0;
        c2 += (fabsf(gi - v.z) <= GHM_DELTA) ? 1 : 0;
        c3 += (fabsf(gi - v.w) <= GHM_DELTA) ? 1 : 0;
    }
    atomicAdd(&count[i], (c0 + c1) + (c2 + c3));
}

// Phase 3: per-i loss terms -> deterministic per-block double partials.
__global__ __launch_bounds__(256) void ghm_finalize(
    const float* __restrict__ logits, const int* __restrict__ targets,
    const float* __restrict__ pos_weight, const int* __restrict__ count,
    double* __restrict__ partials, int n)
{
    __shared__ double red[8];
    const int tid = threadIdx.x;
    const int i = blockIdx.x * 256 + tid;

    double wd = 0.0, pd = 0.0;
    if (i < n) {
        float x = logits[i];
        float y = (float)targets[i];
        float GD = (float)count[i] / GHM_DELTA;
        float beta = (float)n / (GD + GHM_EPS);
        float pw = pos_weight[0];
        float per = pw * y * softplus_ref(-x) + (1.0f - y) * softplus_ref(x);
        wd = (double)(beta * per);
        pd = (double)per;
    }
    #pragma unroll
    for (int off = 32; off >= 1; off >>= 1) {
        wd += __shfl_down(wd, off, 64);
        pd += __shfl_down(pd, off, 64);
    }
    const int wave = tid >> 6;
    if ((tid & 63) == 0) { red[wave * 2] = wd; red[wave * 2 + 1] = pd; }
    __syncthreads();
    if (tid == 0) {
        double sw = 0.0, sp = 0.0;
        for (int k = 0; k < 4; ++k) { sw += red[k * 2]; sp += red[k * 2 + 1]; }
        partials[blockIdx.x * 2]     = sw;
        partials[blockIdx.x * 2 + 1] = sp;
    }
}

// Phase 4: single-wave deterministic final reduce.
__global__ __launch_bounds__(64) void ghm_final_reduce(
    const double* __restrict__ partials, float* __restrict__ out,
    int nblocks, int n)
{
    double sw = 0.0, sp = 0.0;
    for (int k = threadIdx.x; k < nblocks; k += 64) {
        sw += partials[k * 2];
        sp += partials[k * 2 + 1];
    }
    #pragma unroll
    for (int off = 32; off >= 1; off >>= 1) {
        sw += __shfl_down(sw, off, 64);
        sp += __shfl_down(sp, off, 64);
    }
    if (threadIdx.x == 0) {
        out[0] = (float)(sw / (double)n);
        out[1] = (float)(sp / (double)n);
    }
}

extern "C" void kernel_launch(void* const* d_in, const int* in_sizes, int n_in,
                              void* d_out, int out_size, void* d_ws, size_t ws_size,
                              hipStream_t stream) {
    const float* logits     = (const float*)d_in[0];
    const int*   targets    = (const int*)d_in[1];
    const float* pos_weight = (const float*)d_in[2];
    float* out = (float*)d_out;
    const int n = in_sizes[0];           // 16384

    // ws layout: g[n] floats | count[n] ints | partials[(n/256)*2] doubles
    float*  g        = (float*)d_ws;
    int*    count    = (int*)((char*)d_ws + (size_t)n * 4);
    double* partials = (double*)((char*)d_ws + (size_t)n * 8);

    const int ib = n / 256;              // 64 i-blocks

    ghm_prep<<<ib, 256, 0, stream>>>(logits, targets, g, count, n);
    dim3 grid2(ib, NJCHUNK);
    ghm_pair_count<<<grid2, 256, 0, stream>>>(g, count, n);
    ghm_finalize<<<ib, 256, 0, stream>>>(logits, targets, pos_weight, count,
                                         partials, n);
    ghm_final_reduce<<<1, 64, 0, stream>>>(partials, out, ib, n);
}